// Round 6
// baseline (99898.987 us; speedup 1.0000x reference)
//
#include <hip/hip_runtime.h>
#include <math.h>

// ESN scan, round 6: W in LDS (no register-allocator gamble).
// 32 blocks x 256 threads, persistent. Per block: 32 rows of W (DEC-folded,
// 128 KB) in dynamic LDS. Wave w owns rows 8w..8w+7; lane l covers
// k in {4l..4l+3}+256p (p=0..3) -> all W/s LDS reads are uniform-pattern
// ds_read_b128 (full-BW floor). In-register merge-butterfly reduction
// (xor 1,2,4 with row-merge, then xor 8,16,32) -> lane l holds row 8w+(l&7).
// State exchange: u32 packets [tag8|fp24], delegated poll by wave 3
// (8 u64 loads/lane, stale-only reload, light sleep throttle), single
// __syncthreads per step. Output projection decoupled (kernel 2).

#define G_BLOCKS 32
#define TPB      256
#define T_STEPS  32768
#define R_DIM    1024
#define IN_DIM   128
#define OUT_DIM  64

// dynamic LDS layout (bytes)
#define OFF_W    0         // [32][1024] f32   = 131072
#define OFF_S    131072    // [2][1024] f32    =   8192
#define OFF_U    139264    // [2][32]  f32     =    256
#define OFF_X    139520    // [2][128] f32     =   1024
#define OFF_WIN  140544    // [32][132] f32    =  16896
#define SMEM_BYTES 157440

__device__ __forceinline__ float tanh_fast(float y) {
    float e = __expf(2.0f * y);
    return 1.0f - 2.0f / (e + 1.0f);
}
__device__ __forceinline__ unsigned pack24(float v, unsigned tag) {
    unsigned bts = __float_as_uint(v);
    bts = (bts + 0x80u) >> 8;              // |v|<1 -> no carry into tag byte
    return (tag << 24) | (bts & 0x00FFFFFFu);
}
__device__ __forceinline__ float unpack24(unsigned p) {
    return __uint_as_float(p << 8);
}

__global__ __launch_bounds__(TPB, 1)
void esn_scan(const float* __restrict__ x,     // [T][128]
              const float* __restrict__ Win,   // [1024][128]
              const float* __restrict__ W,     // [1024][1024]
              float* __restrict__ states,      // ws: [T][1024]
              unsigned* __restrict__ sbuf)     // ws: [2][1024] u32 packets
{
    extern __shared__ char smem[];
    float* W_lds   = (float*)(smem + OFF_W);
    float* s_lds   = (float*)(smem + OFF_S);
    float* u_lds   = (float*)(smem + OFF_U);
    float* x_lds   = (float*)(smem + OFF_X);
    float* win_lds = (float*)(smem + OFF_WIN);

    constexpr float A = 0.5f, DEC = 0.5f;
    const int b     = blockIdx.x;
    const int tid   = threadIdx.x;
    const int l     = tid & 63;
    const int w     = tid >> 6;            // wave 0..3
    const int myrow = 8 * w + (l & 7);     // local row this lane finalizes
    const int grow  = b * 32 + myrow;

    // ---- setup ----
    // W chunk -> LDS, DEC pre-folded (W @ (DEC*s) == (DEC*W) @ s)
    for (int i = tid; i < 32 * (R_DIM / 4); i += TPB) {
        const int row = i >> 8, g = i & 255;
        float4 v = *(const float4*)(W + (size_t)(b * 32 + row) * R_DIM + 4 * g);
        v.x *= DEC; v.y *= DEC; v.z *= DEC; v.w *= DEC;
        *(float4*)(W_lds + row * R_DIM + 4 * g) = v;
    }
    for (int i = tid; i < 32 * IN_DIM; i += TPB) {
        int rr = i >> 7, cc = i & 127;
        win_lds[rr * 132 + cc] = Win[(size_t)(b * 32 + rr) * IN_DIM + cc];
    }
    for (int i = tid; i < R_DIM; i += TPB) s_lds[i] = 0.f;   // buffer 0: s_0=0
    if (tid < 32) {
        *(float4*)(x_lds + tid * 4)       = *(const float4*)(x + tid * 4);
        *(float4*)(x_lds + 128 + tid * 4) = *(const float4*)(x + IN_DIM + tid * 4);
    }
    float4 xr = make_float4(0.f, 0.f, 0.f, 0.f);   // tid 128..159: x_{t+2}
    if (tid >= 128 && tid < 160)
        xr = *(const float4*)(x + 2 * IN_DIM + (tid - 128) * 4);
    __syncthreads();

    // u_0 (waves 0-1: row=tid>>2, seg=tid&3)
    if (tid < 128) {
        const int row = tid >> 2, seg = tid & 3;
        const float* wl = win_lds + row * 132 + seg * 32;
        const float* xl = x_lds + seg * 32;
        float acc = 0.f;
        #pragma unroll
        for (int j = 0; j < 32; j += 4) {
            float4 wv = *(const float4*)(wl + j);
            float4 xv = *(const float4*)(xl + j);
            acc += wv.x*xv.x + wv.y*xv.y + wv.z*xv.z + wv.w*xv.w;
        }
        acc += __shfl_xor(acc, 1);
        acc += __shfl_xor(acc, 2);
        if (seg == 0) u_lds[row] = acc;
    }
    __syncthreads();

    float s_prev = 0.f;

    for (int t = 0; t < T_STEPS; ++t) {
        // ---- D phase (pre-barrier, disjoint roles) ----
        if (tid < 128) {
            // u_{t+1} -> u_lds[(t+1)&1]
            const int row = tid >> 2, seg = tid & 3;
            const float* wl = win_lds + row * 132 + seg * 32;
            const float* xl = x_lds + ((t + 1) & 1) * 128 + seg * 32;
            float acc = 0.f;
            #pragma unroll
            for (int j = 0; j < 32; j += 4) {
                float4 wv = *(const float4*)(wl + j);
                float4 xv = *(const float4*)(xl + j);
                acc += wv.x*xv.x + wv.y*xv.y + wv.z*xv.z + wv.w*xv.w;
            }
            acc += __shfl_xor(acc, 1);
            acc += __shfl_xor(acc, 2);
            if (seg == 0) u_lds[((t + 1) & 1) * 32 + row] = acc;
        } else if (tid < 160) {
            // commit x_{t+2} into buf t&1, prefetch x_{t+3}
            const int xt = tid - 128;
            *(float4*)(x_lds + (t & 1) * 128 + xt * 4) = xr;
            const int tn = (t + 3 < T_STEPS) ? (t + 3) : (T_STEPS - 1);
            xr = *(const float4*)(x + (size_t)tn * IN_DIM + xt * 4);
        } else if (tid >= 192 && t > 0) {
            // delegated poll: lane l owns rows 16l..16l+15 = 8 u64 loads
            const unsigned long long* sb =
                (const unsigned long long*)(sbuf + (t & 1) * R_DIM) + l * 8;
            const unsigned tg = (unsigned)(t & 255);
            unsigned long long pk[8];
            unsigned valid = 0;
            int pass = 0;
            while (valid != 0xFFu) {
                #pragma unroll
                for (int j = 0; j < 8; ++j)
                    if (!(valid & (1u << j)))
                        pk[j] = __hip_atomic_load(sb + j, __ATOMIC_RELAXED,
                                                  __HIP_MEMORY_SCOPE_AGENT);
                #pragma unroll
                for (int j = 0; j < 8; ++j) {
                    if (!(valid & (1u << j))) {
                        unsigned lo = (unsigned)pk[j], hi = (unsigned)(pk[j] >> 32);
                        if (((lo >> 24) == tg) && ((hi >> 24) == tg))
                            valid |= (1u << j);
                    }
                }
                if (valid != 0xFFu && ++pass > 2) __builtin_amdgcn_s_sleep(1);
            }
            float* dst = s_lds + (t & 1) * R_DIM + l * 16;
            #pragma unroll
            for (int j = 0; j < 8; ++j) {
                dst[2 * j]     = unpack24((unsigned)pk[j]);
                dst[2 * j + 1] = unpack24((unsigned)(pk[j] >> 32));
            }
        }
        // u preload (pre-barrier; u_lds[t&1] was synced by barrier_{t-1})
        const float u_pre = u_lds[(t & 1) * 32 + myrow];
        __syncthreads();

        // ---- F phase: matvec from LDS, uniform b128 pattern ----
        const float* sp = s_lds + (t & 1) * R_DIM;
        const float4 sv0 = *(const float4*)(sp +   0 + 4 * l);
        const float4 sv1 = *(const float4*)(sp + 256 + 4 * l);
        const float4 sv2 = *(const float4*)(sp + 512 + 4 * l);
        const float4 sv3 = *(const float4*)(sp + 768 + 4 * l);
        float a[8];
        #pragma unroll
        for (int i = 0; i < 8; ++i) {
            const float* wr = W_lds + (size_t)(8 * w + i) * R_DIM + 4 * l;
            const float4 w0 = *(const float4*)(wr +   0);
            const float4 w1 = *(const float4*)(wr + 256);
            const float4 w2 = *(const float4*)(wr + 512);
            const float4 w3 = *(const float4*)(wr + 768);
            a[i] = w0.x*sv0.x + w0.y*sv0.y + w0.z*sv0.z + w0.w*sv0.w
                 + w1.x*sv1.x + w1.y*sv1.y + w1.z*sv1.z + w1.w*sv1.w
                 + w2.x*sv2.x + w2.y*sv2.y + w2.z*sv2.z + w2.w*sv2.w
                 + w3.x*sv3.x + w3.y*sv3.y + w3.z*sv3.z + w3.w*sv3.w;
        }
        // merge-butterfly: after xor 1,2,4 lane l holds row (l&7) over its
        // octet; xor 8,16,32 finishes the 64-lane sum.
        float b0, b1, b2, b3;
        {
            const bool hi = l & 1;
            float t0 = __shfl_xor(a[0], 1), t1 = __shfl_xor(a[1], 1);
            b0 = hi ? (a[1] + t1) : (a[0] + t0);
            t0 = __shfl_xor(a[2], 1); t1 = __shfl_xor(a[3], 1);
            b1 = hi ? (a[3] + t1) : (a[2] + t0);
            t0 = __shfl_xor(a[4], 1); t1 = __shfl_xor(a[5], 1);
            b2 = hi ? (a[5] + t1) : (a[4] + t0);
            t0 = __shfl_xor(a[6], 1); t1 = __shfl_xor(a[7], 1);
            b3 = hi ? (a[7] + t1) : (a[6] + t0);
        }
        float c0, c1;
        {
            const bool hi = l & 2;
            float t0 = __shfl_xor(b0, 2), t1 = __shfl_xor(b1, 2);
            c0 = hi ? (b1 + t1) : (b0 + t0);
            float t2 = __shfl_xor(b2, 2), t3 = __shfl_xor(b3, 2);
            c1 = hi ? (b3 + t3) : (b2 + t2);
        }
        float d;
        {
            const bool hi = l & 4;
            float t0 = __shfl_xor(c0, 4), t1 = __shfl_xor(c1, 4);
            d = hi ? (c1 + t1) : (c0 + t0);
        }
        d += __shfl_xor(d, 8);
        d += __shfl_xor(d, 16);
        d += __shfl_xor(d, 32);

        // leak update (consistent across the octet), publish by lanes l<8
        const float snew = DEC * s_prev + A * tanh_fast(u_pre + d);
        s_prev = snew;
        if (l < 8) {
            const unsigned tg1 = (unsigned)((t + 1) & 255);
            __hip_atomic_store(&sbuf[((t + 1) & 1) * R_DIM + grow],
                               pack24(snew, tg1),
                               __ATOMIC_RELAXED, __HIP_MEMORY_SCOPE_AGENT);
            states[(size_t)t * R_DIM + grow] = snew;
        }
    }
}

// ---- kernel 2: out = states @ Wout ----
__global__ __launch_bounds__(256)
void out_gemm(const float* __restrict__ states,
              const float* __restrict__ Wout,
              float* __restrict__ out)
{
    __shared__ float st[64][132];
    __shared__ float wt[128][64];
    const int t0  = blockIdx.x * 64;
    const int tid = threadIdx.x;
    const int tl  = tid >> 2;
    const int cg  = tid & 3;
    float acc[16];
    #pragma unroll
    for (int j = 0; j < 16; ++j) acc[j] = 0.f;

    for (int kt = 0; kt < R_DIM; kt += 128) {
        const float* src = states + (size_t)(t0 + tl) * R_DIM + kt + cg * 32;
        #pragma unroll
        for (int q = 0; q < 8; ++q)
            *(float4*)&st[tl][cg * 32 + q * 4] = *(const float4*)(src + q * 4);
        const float* wsrc = Wout + (size_t)(kt + (tid >> 1)) * OUT_DIM + (tid & 1) * 32;
        #pragma unroll
        for (int q = 0; q < 8; ++q)
            *(float4*)&wt[tid >> 1][(tid & 1) * 32 + q * 4] = *(const float4*)(wsrc + q * 4);
        __syncthreads();
        #pragma unroll 4
        for (int k = 0; k < 128; ++k) {
            const float s = st[tl][k];
            const float* wr = &wt[k][cg * 16];
            #pragma unroll
            for (int j = 0; j < 16; ++j) acc[j] += s * wr[j];
        }
        __syncthreads();
    }
    float* op = out + (size_t)(t0 + tl) * OUT_DIM + cg * 16;
    #pragma unroll
    for (int q = 0; q < 4; ++q) *(float4*)(op + q * 4) = *(float4*)&acc[q * 4];
}

extern "C" void kernel_launch(void* const* d_in, const int* in_sizes, int n_in,
                              void* d_out, int out_size, void* d_ws, size_t ws_size,
                              hipStream_t stream) {
    const float* x    = (const float*)d_in[0];
    const float* Win  = (const float*)d_in[1];
    const float* W    = (const float*)d_in[2];
    const float* Wout = (const float*)d_in[3];
    float* out = (float*)d_out;

    unsigned* sbuf = (unsigned*)d_ws;                 // 8 KB used
    float* states  = (float*)((char*)d_ws + 65536);   // 128 MiB

    hipFuncSetAttribute((const void*)esn_scan,
                        hipFuncAttributeMaxDynamicSharedMemorySize, SMEM_BYTES);
    esn_scan<<<G_BLOCKS, TPB, SMEM_BYTES, stream>>>(x, Win, W, states, sbuf);
    out_gemm<<<T_STEPS / 64, 256, 0, stream>>>(states, Wout, out);
}